// Round 7
// baseline (2869.723 us; speedup 1.0000x reference)
//
#include <hip/hip_runtime.h>
#include <stdint.h>

#define BATCH   4
#define NPTS    16384
#define NPOINT  1024
#define KNN     20
#define KSEL    21   // K+1, includes self

// ---------------------------------------------------------------------------
// FPS: one block per batch. Points + min_d held in REGISTERS via
// ext_vector_type(32) — r6 showed plain local arrays (512 B) exceed the
// AMDGPUPromoteAlloca budget and land in scratch: VGPR_Count=84,
// FETCH_SIZE=411 MB of scratch re-reads, 5540 cyc/iter. First-class LLVM
// vectors cannot be demoted to scratch by that pass; after #pragma unroll all
// subscripts are constant insert/extractelement. Per-element FP op sequence
// is IDENTICAL to the validated r5 binary (sub,mul,mul,mul,add,add,min,cmp) —
// selection results cannot change.
// ---------------------------------------------------------------------------
#define FPS_THREADS 512
#define PPT (NPTS / FPS_THREADS)  // 32 points per thread, strided layout

typedef float vf32x32 __attribute__((ext_vector_type(32)));

__global__ __launch_bounds__(FPS_THREADS, 2)
void fps_kernel(const float* __restrict__ pts, float* __restrict__ out,
                int* __restrict__ ws_ind, float* __restrict__ ws_query) {
  const int b = blockIdx.x;
  const float* P = pts + (size_t)b * NPTS * 3;
  float* out_ind = out;                   // [B,NPOINT] (indices as float)
  float* out_q   = out + BATCH * NPOINT;  // [B,NPOINT,3]
  const int t = threadIdx.x;

  vf32x32 px, py, pz, md;
#pragma unroll
  for (int i = 0; i < PPT; ++i) {
    int idx = i * FPS_THREADS + t;        // strided: global idx = i*512 + t
    px[i] = P[idx * 3 + 0];
    py[i] = P[idx * 3 + 1];
    pz[i] = P[idx * 3 + 2];
    md[i] = 1e10f;
  }

  // parity double-buffered reduce slots: one barrier per iteration
  __shared__ float s_val[2][FPS_THREADS / 64];
  __shared__ int   s_idx[2][FPS_THREADS / 64];

  if (t == 0) {
    out_ind[b * NPOINT] = 0.0f;
    ws_ind[b * NPOINT]  = 0;
    float ax = P[0], ay = P[1], az = P[2];
    out_q[(size_t)(b * NPOINT) * 3 + 0] = ax;
    out_q[(size_t)(b * NPOINT) * 3 + 1] = ay;
    out_q[(size_t)(b * NPOINT) * 3 + 2] = az;
    ws_query[(size_t)(b * NPOINT) * 3 + 0] = ax;
    ws_query[(size_t)(b * NPOINT) * 3 + 1] = ay;
    ws_query[(size_t)(b * NPOINT) * 3 + 2] = az;
  }
  // current selected point (index 0 to start) — broadcast load
  float qx = P[0], qy = P[1], qz = P[2];

  for (int it = 1; it < NPOINT; ++it) {
    const int p = it & 1;
    float best = -1.0f;
    int bi = 0;
#pragma unroll
    for (int i = 0; i < PPT; ++i) {
      float dx = __fsub_rn(px[i], qx);
      float dy = __fsub_rn(py[i], qy);
      float dz = __fsub_rn(pz[i], qz);
      float d  = __fadd_rn(__fadd_rn(__fmul_rn(dx, dx), __fmul_rn(dy, dy)),
                           __fmul_rn(dz, dz));
      float m = fminf(md[i], d);
      md[i] = m;
      // within-thread: local indices ascend with i, strict > keeps first max
      if (m > best) { best = m; bi = i; }
    }
    int bidx = bi * FPS_THREADS + t;

    // wave argmax reduce, tie -> lower global index
#pragma unroll
    for (int off = 32; off >= 1; off >>= 1) {
      float ov = __shfl_down(best, off);
      int   oi = __shfl_down(bidx, off);
      if (ov > best || (ov == best && oi < bidx)) { best = ov; bidx = oi; }
    }

    if ((t & 63) == 0) { s_val[p][t >> 6] = best; s_idx[p][t >> 6] = bidx; }
    __syncthreads();

    // every thread reduces the 8 wave candidates (redundant, uniform result)
    float bv = s_val[p][0];
    int   bx = s_idx[p][0];
#pragma unroll
    for (int w = 1; w < FPS_THREADS / 64; ++w) {
      float v = s_val[p][w];
      int   x = s_idx[p][w];
      if (v > bv || (v == bv && x < bx)) { bv = v; bx = x; }
    }

    // broadcast load of winner coords (same address across lanes)
    qx = P[bx * 3 + 0];
    qy = P[bx * 3 + 1];
    qz = P[bx * 3 + 2];

    if (t == 0) {
      out_ind[b * NPOINT + it] = (float)bx;
      ws_ind[b * NPOINT + it]  = bx;
      size_t o = (size_t)(b * NPOINT + it) * 3;
      out_q[o + 0] = qx; out_q[o + 1] = qy; out_q[o + 2] = qz;
      ws_query[o + 0] = qx; ws_query[o + 1] = qy; ws_query[o + 2] = qz;
    }
  }
}

// ---------------------------------------------------------------------------
// KNN: one wave per query. Replicates the numpy reference rounding exactly
// (VALIDATED r5/r6, absmax 0.0 — do not change FP semantics):
//   qq,pp : ((x*x + y*y) + z*z), plain rn per op   (contract(off))
//   dot   : fma(z,z', fma(y,y', rn(x*x')))         (BLAS sgemm chain)
//   d     : (qq + pp) - 2*dot, plain rn; max(d, 0)
// Top-(K+1) via u64 key (dist_bits<<32)|idx == stable ascending order;
// per-lane sorted insert, then 21-round wave-min merge; rank 0 dropped.
// ---------------------------------------------------------------------------
#define KNN_WAVES 4

__global__ __launch_bounds__(256)
void knn_kernel(const float* __restrict__ cand_base,   // [B, ncand, 3]
                const float* __restrict__ query_base,  // [B, NPOINT, 3]
                int ncand,
                float* __restrict__ out_nbr,           // [B, NPOINT, K]
                float* __restrict__ out_d) {           // [B, NPOINT, K, 3]
#pragma clang fp contract(off)
  const int wid_in_blk = threadIdx.x >> 6;
  const int w    = blockIdx.x * KNN_WAVES + wid_in_blk;
  const int lane = threadIdx.x & 63;
  const int b    = w / NPOINT;
  const int qi   = w % NPOINT;

  const float* C = cand_base + (size_t)b * ncand * 3;
  const float* Q = query_base + ((size_t)b * NPOINT + qi) * 3;
  const float qx = Q[0], qy = Q[1], qz = Q[2];
  const float qq = (qx * qx + qy * qy) + qz * qz;

  unsigned long long best[KSEL];
#pragma unroll
  for (int j = 0; j < KSEL; ++j) best[j] = 0xFFFFFFFFFFFFFFFFull;

  for (int j = lane; j < ncand; j += 64) {
    float px = C[j * 3 + 0], py = C[j * 3 + 1], pz = C[j * 3 + 2];
    float pp  = (px * px + py * py) + pz * pz;
    // BLAS sgemm inner product: FMA accumulate, k ascending, acc starts 0
    float dot = __builtin_fmaf(qz, pz, __builtin_fmaf(qy, py, qx * px));
    float d = (qq + pp) - 2.0f * dot;
    d = fmaxf(d, 0.0f);
    unsigned long long key =
        ((unsigned long long)__float_as_uint(d) << 32) | (unsigned int)j;
    if (key < best[KSEL - 1]) {
      unsigned long long c = key;
#pragma unroll
      for (int s = 0; s < KSEL; ++s) {
        unsigned long long o = best[s];
        bool l = c < o;
        unsigned long long nb = l ? c : o;
        c = l ? o : c;
        best[s] = nb;
      }
    }
  }

  // dump each lane's sorted list to LDS
  __shared__ unsigned long long s_list[KNN_WAVES][64 * KSEL];
  unsigned long long* L = s_list[wid_in_blk];
#pragma unroll
  for (int j = 0; j < KSEL; ++j) L[lane * KSEL + j] = best[j];
  __syncthreads();

  int hp = 0;      // per-lane head pointer into its own sorted list
  int myK = -1, myIdx = 0;
  for (int r = 0; r < KSEL; ++r) {
    unsigned long long v = L[lane * KSEL + hp];
    int src = lane;
#pragma unroll
    for (int off = 32; off >= 1; off >>= 1) {
      unsigned long long ov = __shfl_down(v, off);
      int os = __shfl_down(src, off);
      if (ov < v) { v = ov; src = os; }  // keys unique (idx embedded)
    }
    v   = __shfl(v, 0);
    src = __shfl(src, 0);
    if (lane == src) hp++;
    if (r >= 1 && lane == r - 1) {       // drop r==0 (self)
      myIdx = (int)(unsigned int)(v & 0xFFFFFFFFull);
      myK = r - 1;
    }
  }

  if (myK >= 0) {  // lanes 0..19 write neighbor k = lane
    size_t o = (size_t)(b * NPOINT + qi) * KNN + myK;
    out_nbr[o] = (float)myIdx;
    float sx = C[myIdx * 3 + 0], sy = C[myIdx * 3 + 1], sz = C[myIdx * 3 + 2];
    out_d[o * 3 + 0] = qx - sx;
    out_d[o * 3 + 1] = qy - sy;
    out_d[o * 3 + 2] = qz - sz;
  }
}

// ---------------------------------------------------------------------------
extern "C" void kernel_launch(void* const* d_in, const int* in_sizes, int n_in,
                              void* d_out, int out_size, void* d_ws,
                              size_t ws_size, hipStream_t stream) {
  (void)in_sizes; (void)n_in; (void)out_size; (void)ws_size;
  const float* pts = (const float*)d_in[0];
  float* out = (float*)d_out;

  int*   ws_ind   = (int*)d_ws;
  float* ws_query = (float*)((char*)d_ws + (size_t)BATCH * NPOINT * sizeof(int));

  // output layout (floats): [xyz_ind | xyz_query | nbr_mid | d_mid | nbr_out | d_out]
  float* out_nbr_mid = out + (size_t)BATCH * NPOINT * 4;            // 16384
  float* out_d_mid   = out_nbr_mid + (size_t)BATCH * NPOINT * KNN;  // +81920
  float* out_nbr_out = out_d_mid + (size_t)BATCH * NPOINT * KNN * 3;
  float* out_d_out   = out_nbr_out + (size_t)BATCH * NPOINT * KNN;

  hipLaunchKernelGGL(fps_kernel, dim3(BATCH), dim3(FPS_THREADS), 0, stream,
                     pts, out, ws_ind, ws_query);

  hipLaunchKernelGGL(knn_kernel, dim3(BATCH * NPOINT / KNN_WAVES), dim3(256),
                     0, stream, pts, ws_query, NPTS, out_nbr_mid, out_d_mid);

  hipLaunchKernelGGL(knn_kernel, dim3(BATCH * NPOINT / KNN_WAVES), dim3(256),
                     0, stream, ws_query, ws_query, NPOINT, out_nbr_out,
                     out_d_out);
}

// Round 8
// 2808.994 us; speedup vs baseline: 1.0216x; 1.0216x over previous
//
#include <hip/hip_runtime.h>
#include <stdint.h>

#define BATCH   4
#define NPTS    16384
#define NPOINT  1024
#define KNN     20
#define KSEL    21   // K+1, includes self

// ---------------------------------------------------------------------------
// FPS: one block per batch. r5/r6/r7 all compiled to IDENTICAL code
// (VGPR=84, FETCH=411MB = 100KB/block-iter of px/py/pz re-reads): the
// compiler remats the loop-invariant coordinate loads every iteration
// instead of keeping 128 floats live. Fix: 128 NAMED scalars (no alloca,
// no vector) + empty asm barrier on each init load -> not rematerializable,
// not CSE-able; compiler must keep the bits in VGPRs. waves_per_eu(2,2)
// pins the occupancy target (budget 512/2 = 256 VGPRs).
// Per-point FP op sequence is IDENTICAL to the validated r5 binary —
// selection results cannot change.
// ---------------------------------------------------------------------------
#define FPS_THREADS 512
#define PPT (NPTS / FPS_THREADS)  // 32 points per thread, strided layout

__device__ __forceinline__ float opaque_f(float x) {
  __asm__ volatile("" : "+v"(x));
  return x;
}

#define REPEAT32(M) \
  M(0) M(1) M(2) M(3) M(4) M(5) M(6) M(7) \
  M(8) M(9) M(10) M(11) M(12) M(13) M(14) M(15) \
  M(16) M(17) M(18) M(19) M(20) M(21) M(22) M(23) \
  M(24) M(25) M(26) M(27) M(28) M(29) M(30) M(31)

#define FPS_DECL(i) float px##i, py##i, pz##i, md##i;

#define FPS_INIT(i) { \
    int idx = (i) * FPS_THREADS + t; \
    px##i = opaque_f(P[idx * 3 + 0]); \
    py##i = opaque_f(P[idx * 3 + 1]); \
    pz##i = opaque_f(P[idx * 3 + 2]); \
    md##i = 1e10f; }

#define FPS_STEP(i) { \
    float dx = __fsub_rn(px##i, qx); \
    float dy = __fsub_rn(py##i, qy); \
    float dz = __fsub_rn(pz##i, qz); \
    float d  = __fadd_rn(__fadd_rn(__fmul_rn(dx, dx), __fmul_rn(dy, dy)), \
                         __fmul_rn(dz, dz)); \
    float m = fminf(md##i, d); \
    md##i = m; \
    bool g = (m > best); \
    best = g ? m : best; \
    bi   = g ? (i) : bi; }

__global__ __launch_bounds__(FPS_THREADS)
__attribute__((amdgpu_waves_per_eu(2, 2)))
void fps_kernel(const float* __restrict__ pts, float* __restrict__ out,
                int* __restrict__ ws_ind, float* __restrict__ ws_query) {
  const int b = blockIdx.x;
  const float* P = pts + (size_t)b * NPTS * 3;
  float* out_ind = out;                   // [B,NPOINT] (indices as float)
  float* out_q   = out + BATCH * NPOINT;  // [B,NPOINT,3]
  const int t = threadIdx.x;

  REPEAT32(FPS_DECL)
  REPEAT32(FPS_INIT)

  // parity double-buffered reduce slots: one barrier per iteration
  __shared__ float s_val[2][FPS_THREADS / 64];
  __shared__ int   s_idx[2][FPS_THREADS / 64];

  if (t == 0) {
    out_ind[b * NPOINT] = 0.0f;
    ws_ind[b * NPOINT]  = 0;
    float ax = P[0], ay = P[1], az = P[2];
    out_q[(size_t)(b * NPOINT) * 3 + 0] = ax;
    out_q[(size_t)(b * NPOINT) * 3 + 1] = ay;
    out_q[(size_t)(b * NPOINT) * 3 + 2] = az;
    ws_query[(size_t)(b * NPOINT) * 3 + 0] = ax;
    ws_query[(size_t)(b * NPOINT) * 3 + 1] = ay;
    ws_query[(size_t)(b * NPOINT) * 3 + 2] = az;
  }
  // current selected point (index 0 to start) — broadcast load
  float qx = P[0], qy = P[1], qz = P[2];

  for (int it = 1; it < NPOINT; ++it) {
    const int p = it & 1;
    float best = -1.0f;
    int bi = 0;
    REPEAT32(FPS_STEP)
    int bidx = bi * FPS_THREADS + t;

    // wave argmax reduce, tie -> lower global index
#pragma unroll
    for (int off = 32; off >= 1; off >>= 1) {
      float ov = __shfl_down(best, off);
      int   oi = __shfl_down(bidx, off);
      if (ov > best || (ov == best && oi < bidx)) { best = ov; bidx = oi; }
    }

    if ((t & 63) == 0) { s_val[p][t >> 6] = best; s_idx[p][t >> 6] = bidx; }
    __syncthreads();

    // every thread reduces the 8 wave candidates (redundant, uniform result)
    float bv = s_val[p][0];
    int   bx = s_idx[p][0];
#pragma unroll
    for (int w = 1; w < FPS_THREADS / 64; ++w) {
      float v = s_val[p][w];
      int   x = s_idx[p][w];
      if (v > bv || (v == bv && x < bx)) { bv = v; bx = x; }
    }

    // broadcast load of winner coords (same address across lanes, L1-hot)
    qx = P[bx * 3 + 0];
    qy = P[bx * 3 + 1];
    qz = P[bx * 3 + 2];

    if (t == 0) {
      out_ind[b * NPOINT + it] = (float)bx;
      ws_ind[b * NPOINT + it]  = bx;
      size_t o = (size_t)(b * NPOINT + it) * 3;
      out_q[o + 0] = qx; out_q[o + 1] = qy; out_q[o + 2] = qz;
      ws_query[o + 0] = qx; ws_query[o + 1] = qy; ws_query[o + 2] = qz;
    }
  }
}

// ---------------------------------------------------------------------------
// KNN: one wave per query. Replicates the numpy reference rounding exactly
// (VALIDATED r5/r6/r7, absmax 0.0 — do not change FP semantics):
//   qq,pp : ((x*x + y*y) + z*z), plain rn per op   (contract(off))
//   dot   : fma(z,z', fma(y,y', rn(x*x')))         (BLAS sgemm chain)
//   d     : (qq + pp) - 2*dot, plain rn; max(d, 0)
// Top-(K+1) via u64 key (dist_bits<<32)|idx == stable ascending order;
// per-lane sorted insert, then 21-round wave-min merge; rank 0 dropped.
// ---------------------------------------------------------------------------
#define KNN_WAVES 4

__global__ __launch_bounds__(256)
void knn_kernel(const float* __restrict__ cand_base,   // [B, ncand, 3]
                const float* __restrict__ query_base,  // [B, NPOINT, 3]
                int ncand,
                float* __restrict__ out_nbr,           // [B, NPOINT, K]
                float* __restrict__ out_d) {           // [B, NPOINT, K, 3]
#pragma clang fp contract(off)
  const int wid_in_blk = threadIdx.x >> 6;
  const int w    = blockIdx.x * KNN_WAVES + wid_in_blk;
  const int lane = threadIdx.x & 63;
  const int b    = w / NPOINT;
  const int qi   = w % NPOINT;

  const float* C = cand_base + (size_t)b * ncand * 3;
  const float* Q = query_base + ((size_t)b * NPOINT + qi) * 3;
  const float qx = Q[0], qy = Q[1], qz = Q[2];
  const float qq = (qx * qx + qy * qy) + qz * qz;

  unsigned long long best[KSEL];
#pragma unroll
  for (int j = 0; j < KSEL; ++j) best[j] = 0xFFFFFFFFFFFFFFFFull;

  for (int j = lane; j < ncand; j += 64) {
    float px = C[j * 3 + 0], py = C[j * 3 + 1], pz = C[j * 3 + 2];
    float pp  = (px * px + py * py) + pz * pz;
    // BLAS sgemm inner product: FMA accumulate, k ascending, acc starts 0
    float dot = __builtin_fmaf(qz, pz, __builtin_fmaf(qy, py, qx * px));
    float d = (qq + pp) - 2.0f * dot;
    d = fmaxf(d, 0.0f);
    unsigned long long key =
        ((unsigned long long)__float_as_uint(d) << 32) | (unsigned int)j;
    if (key < best[KSEL - 1]) {
      unsigned long long c = key;
#pragma unroll
      for (int s = 0; s < KSEL; ++s) {
        unsigned long long o = best[s];
        bool l = c < o;
        unsigned long long nb = l ? c : o;
        c = l ? o : c;
        best[s] = nb;
      }
    }
  }

  // dump each lane's sorted list to LDS
  __shared__ unsigned long long s_list[KNN_WAVES][64 * KSEL];
  unsigned long long* L = s_list[wid_in_blk];
#pragma unroll
  for (int j = 0; j < KSEL; ++j) L[lane * KSEL + j] = best[j];
  __syncthreads();

  int hp = 0;      // per-lane head pointer into its own sorted list
  int myK = -1, myIdx = 0;
  for (int r = 0; r < KSEL; ++r) {
    unsigned long long v = L[lane * KSEL + hp];
    int src = lane;
#pragma unroll
    for (int off = 32; off >= 1; off >>= 1) {
      unsigned long long ov = __shfl_down(v, off);
      int os = __shfl_down(src, off);
      if (ov < v) { v = ov; src = os; }  // keys unique (idx embedded)
    }
    v   = __shfl(v, 0);
    src = __shfl(src, 0);
    if (lane == src) hp++;
    if (r >= 1 && lane == r - 1) {       // drop r==0 (self)
      myIdx = (int)(unsigned int)(v & 0xFFFFFFFFull);
      myK = r - 1;
    }
  }

  if (myK >= 0) {  // lanes 0..19 write neighbor k = lane
    size_t o = (size_t)(b * NPOINT + qi) * KNN + myK;
    out_nbr[o] = (float)myIdx;
    float sx = C[myIdx * 3 + 0], sy = C[myIdx * 3 + 1], sz = C[myIdx * 3 + 2];
    out_d[o * 3 + 0] = qx - sx;
    out_d[o * 3 + 1] = qy - sy;
    out_d[o * 3 + 2] = qz - sz;
  }
}

// ---------------------------------------------------------------------------
extern "C" void kernel_launch(void* const* d_in, const int* in_sizes, int n_in,
                              void* d_out, int out_size, void* d_ws,
                              size_t ws_size, hipStream_t stream) {
  (void)in_sizes; (void)n_in; (void)out_size; (void)ws_size;
  const float* pts = (const float*)d_in[0];
  float* out = (float*)d_out;

  int*   ws_ind   = (int*)d_ws;
  float* ws_query = (float*)((char*)d_ws + (size_t)BATCH * NPOINT * sizeof(int));

  // output layout (floats): [xyz_ind | xyz_query | nbr_mid | d_mid | nbr_out | d_out]
  float* out_nbr_mid = out + (size_t)BATCH * NPOINT * 4;            // 16384
  float* out_d_mid   = out_nbr_mid + (size_t)BATCH * NPOINT * KNN;  // +81920
  float* out_nbr_out = out_d_mid + (size_t)BATCH * NPOINT * KNN * 3;
  float* out_d_out   = out_nbr_out + (size_t)BATCH * NPOINT * KNN;

  hipLaunchKernelGGL(fps_kernel, dim3(BATCH), dim3(FPS_THREADS), 0, stream,
                     pts, out, ws_ind, ws_query);

  hipLaunchKernelGGL(knn_kernel, dim3(BATCH * NPOINT / KNN_WAVES), dim3(256),
                     0, stream, pts, ws_query, NPTS, out_nbr_mid, out_d_mid);

  hipLaunchKernelGGL(knn_kernel, dim3(BATCH * NPOINT / KNN_WAVES), dim3(256),
                     0, stream, ws_query, ws_query, NPOINT, out_nbr_out,
                     out_d_out);
}